// Round 17
// baseline (119.975 us; speedup 1.0000x reference)
//
#include <hip/hip_runtime.h>

typedef unsigned short u16;
typedef short  bf16x8 __attribute__((ext_vector_type(8)));
typedef u16    u16x8  __attribute__((ext_vector_type(8)));
typedef float  f32x4  __attribute__((ext_vector_type(4)));
typedef float  f32x2  __attribute__((ext_vector_type(2)));
typedef int    i32x4  __attribute__((ext_vector_type(4)));
typedef unsigned u32x4 __attribute__((ext_vector_type(4)));

__device__ __forceinline__ u16 f2bf(float f) {
  union { float f; unsigned u; } x; x.f = f;
  return (u16)((x.u + 0x7fffu + ((x.u >> 16) & 1u)) >> 16);
}

__device__ __forceinline__ unsigned pk2bf(float a, float b) {
  unsigned r;
  asm("v_cvt_pk_bf16_f32 %0, %1, %2" : "=v"(r) : "v"(a), "v"(b));
  return r;
}

__device__ __forceinline__ float exp2v(float x) {
  float r;
  asm("v_exp_f32 %0, %1" : "=v"(r) : "v"(x));
  return r;
}

// async global->LDS, 16B per lane; lds base wave-uniform (HW adds lane*16)
__device__ __forceinline__ void gload16(const void* g, void* lds) {
  __builtin_amdgcn_global_load_lds((const __attribute__((address_space(1))) unsigned int*)g,
                                   (__attribute__((address_space(3))) unsigned int*)lds,
                                   16, 0, 0);
}

// ---- 64-col tiles (128B rows): XOR-swizzled b128 read (2-way max) ----
__device__ __forceinline__ bf16x8 lds8(const u16* base, int row, int colb) {
  int off = (row << 7) + colb;
  off ^= (row & 7) << 4;
  return *(const bf16x8*)((const char*)base + off);
}

// ---- 32-col tiles (64B rows), gemm_out BK=32 ----
__device__ __forceinline__ bf16x8 lds32(const u16* base, int row, int lg) {
  int off = (row << 6) + ((lg ^ ((row >> 1) & 3)) << 4);
  return *(const bf16x8*)((const char*)base + off);
}

// ---------------- merged prep kernel ----------------
// blocks [0,2048): cast x -> bf16; [2048,3072): tiled transpose+cast of 4 weights;
// [3072,3328): RoPE cos/sin table.

__global__ __launch_bounds__(256) void prep_k(const float* __restrict__ x,
                                              const float* __restrict__ Wq,
                                              const float* __restrict__ Wk,
                                              const float* __restrict__ Wv,
                                              const float* __restrict__ Wo,
                                              u16* __restrict__ xb,
                                              u16* __restrict__ WqkvT,
                                              u16* __restrict__ WoT,
                                              f32x2* __restrict__ ctab) {
  __shared__ u16 tile[64][72];
  const int bid = blockIdx.x;
  const int t = threadIdx.x;

  if (bid < 2048) {
    int i = (bid * 256 + t) * 8;
    float4 a = *(const float4*)&x[i];
    float4 b = *(const float4*)&x[i + 4];
    u16x8 o;
    o[0] = f2bf(a.x); o[1] = f2bf(a.y); o[2] = f2bf(a.z); o[3] = f2bf(a.w);
    o[4] = f2bf(b.x); o[5] = f2bf(b.y); o[6] = f2bf(b.z); o[7] = f2bf(b.w);
    *(u16x8*)&xb[i] = o;
  } else if (bid < 3072) {
    int b2 = bid - 2048;
    int z = b2 >> 8, rem = b2 & 255;
    int k0 = (rem >> 4) << 6, nn0 = (rem & 15) << 6;
    const float* W = (z == 0) ? Wq : (z == 1) ? Wk : (z == 2) ? Wv : Wo;
    u16* dst = (z < 3) ? (WqkvT + z * 1024 * 1024) : WoT;
#pragma unroll
    for (int p = 0; p < 4; ++p) {
      int kr = (p << 4) + (t >> 4), c4 = (t & 15) << 2;
      float4 v = *(const float4*)&W[(k0 + kr) * 1024 + nn0 + c4];
      tile[c4 + 0][kr] = f2bf(v.x); tile[c4 + 1][kr] = f2bf(v.y);
      tile[c4 + 2][kr] = f2bf(v.z); tile[c4 + 3][kr] = f2bf(v.w);
    }
    __syncthreads();
#pragma unroll
    for (int p = 0; p < 2; ++p) {
      int nr = (p << 5) + (t >> 3), c8 = (t & 7) << 3;
      i32x4 vv = *(const i32x4*)&tile[nr][c8];
      *(i32x4*)&dst[(nn0 + nr) * 1024 + k0 + c8] = vv;
    }
  } else {
    int idx = (bid - 3072) * 256 + t;
    int i = idx & 31, p = idx >> 5;
    float freq = powf(10000.0f, -(float)(2 * i) * (1.0f / 64.0f));
    float ang = (float)p * freq;
    f32x2 v; v[0] = cosf(ang); v[1] = sinf(ang);
    ctab[idx] = v;
  }
}

// ---------------- fused QKV GEMM (BK=64 super-phases, attn-mirror schedule) ----------------
// 128x128 tile, BK=64 per phase: 2 super-buffers (A,B each 128x64 = 16KB), 64KB LDS,
// 2 blocks/CU. Per phase: stage(next) issued FIRST (whole phase to land), 32 MFMA +
// 16 b128 reads per wave, ONE vmcnt(0)+barrier -> 16 barriers total (was 32).
// Grid 768 (1D, XCD swizzle: 4 M-rows x 24 N per XCD).
// n-region 0: Q (RoPE * 0.125*log2e), 1: K (RoPE), 2: V (transposed per-(b,h),
// sigma key-permuted).

__global__ __launch_bounds__(256) void gemm_qkv_k(const u16* __restrict__ A,
                                                  const u16* __restrict__ BT,
                                                  u16* __restrict__ Qb,
                                                  u16* __restrict__ Kb,
                                                  u16* __restrict__ VbT,
                                                  const f32x2* __restrict__ ctab) {
  __shared__ u16 As[2][128 * 64];   // 16KB per buf
  __shared__ u16 Bs[2][128 * 64];
  const int K = 1024;
  const int lin = blockIdx.x;
  const int xcd = lin & 7, idx = lin >> 3;       // idx 0..95
  const int by = (xcd << 2) + idx / 24;          // 4 M-rows per XCD
  const int bx = idx % 24;
  const int m0 = by << 7, n0 = bx << 7;
  const int t = threadIdx.x, w = t >> 6, l = t & 63;
  const int wr = (w >> 1) << 6, wc = (w & 1) << 6;
  const int lr = l & 15, lg = l >> 4;
  const int srow = l >> 3;
  const int scol = ((l & 7) ^ srow) << 3;        // inverse swizzle for lds8 reads

  // stage one 128x64 A-tile + B-tile: 16 segs of 8 rows each; 4 segs/wave each
  auto stage = [&](int buf, int st) {
    const int k0_ = st << 6;
#pragma unroll
    for (int it = 0; it < 4; ++it) {
      int seg = (w << 2) + it;
      int row = (seg << 3) + srow;
      gload16(&A[(m0 + row) * K + k0_ + scol], (char*)As[buf] + seg * 1024);
      gload16(&BT[(n0 + row) * K + k0_ + scol], (char*)Bs[buf] + seg * 1024);
    }
  };

  f32x4 acc[4][4] = {};

  stage(0, 0);
  asm volatile("s_waitcnt vmcnt(0)" ::: "memory");
  __builtin_amdgcn_s_barrier();
  __builtin_amdgcn_sched_barrier(0);

  for (int st = 0; st < 16; ++st) {
    const int buf = st & 1;
    if (st < 15) stage(buf ^ 1, st + 1);   // issued first: whole phase to land

    const u16* Ab = As[buf];
    const u16* Bb = Bs[buf];
#pragma unroll
    for (int kk = 0; kk < 2; ++kk) {
      bf16x8 af[4], bfr[4];
#pragma unroll
      for (int m = 0; m < 4; ++m) af[m] = lds8(Ab, wr + (m << 4) + lr, (kk << 6) + (lg << 4));
#pragma unroll
      for (int n = 0; n < 4; ++n) bfr[n] = lds8(Bb, wc + (n << 4) + lr, (kk << 6) + (lg << 4));
      __builtin_amdgcn_s_setprio(1);
#pragma unroll
      for (int m = 0; m < 4; ++m)
#pragma unroll
        for (int n = 0; n < 4; ++n)
          acc[m][n] = __builtin_amdgcn_mfma_f32_16x16x32_bf16(af[m], bfr[n], acc[m][n], 0, 0, 0);
      __builtin_amdgcn_s_setprio(0);
    }

    asm volatile("s_waitcnt vmcnt(0)" ::: "memory");
    __builtin_amdgcn_s_barrier();
    __builtin_amdgcn_sched_barrier(0);
  }

  const int region = n0 >> 10;
  if (region < 2) {
    const float qscale = 0.125f * 1.44269504088896f;
#pragma unroll
    for (int m = 0; m < 4; ++m)
#pragma unroll
      for (int n = 0; n < 4; ++n) {
        const int col = n0 + wc + (n << 4) + lr;
        const int hd = col & 63;
#pragma unroll
        for (int r = 0; r < 4; ++r) {
          const int row = m0 + wr + (m << 4) + (lg << 2) + r;
          float v = acc[m][n][r];
          float p = __shfl_xor(v, 1);
          f32x2 cs = ctab[(row & 2047) * 32 + (hd >> 1)];
          float o = (hd & 1) ? (p * cs[1] + v * cs[0]) : (v * cs[0] - p * cs[1]);
          if (region == 0) { o *= qscale; Qb[row * 1024 + (col & 1023)] = f2bf(o); }
          else             { Kb[row * 1024 + (col & 1023)] = f2bf(o); }
        }
      }
  } else {
#pragma unroll
    for (int m = 0; m < 4; ++m)
#pragma unroll
      for (int n = 0; n < 4; ++n) {
        const int cv = n0 + wc + (n << 4) + lr - 2048;
        const int hh = cv >> 6, dim = cv & 63;
#pragma unroll
        for (int r = 0; r < 4; ++r) {
          const int row = m0 + wr + (m << 4) + (lg << 2) + r;
          const int bb = row >> 11, pos = row & 2047;
          // sigma key-permute within each 64-key block
          const int k6 = pos & 63;
          const int pp = (k6 & 3) | (((k6 >> 4) & 1) << 2) | (((k6 >> 2) & 3) << 3)
                       | (((k6 >> 5) & 1) << 5);
          const int posp = (pos & ~63) | pp;
          VbT[(((bb << 4) + hh) << 6 | dim) * 2048 + posp] = f2bf(acc[m][n][r]);
        }
      }
  }
}

// ---------------- output GEMM: out = Ob * WoT^T, fp32 out ----------------
// grid 512 (1D, XCD swizzle: 8 M-rows x 8 N per XCD), 2-way LDS swizzle.

__global__ __launch_bounds__(256) void gemm_out_k(const u16* __restrict__ A,
                                                  const u16* __restrict__ BT,
                                                  float* __restrict__ C) {
  __shared__ u16 As[3][64 * 32];
  __shared__ u16 Bs[3][128 * 32];
  const int K = 1024;
  const int lin = blockIdx.x;
  const int xcd = lin & 7, idx = lin >> 3;       // idx 0..63
  const int by = (xcd << 3) + (idx >> 3);        // 8 M-rows per XCD
  const int bx = idx & 7;
  const int m0 = by << 6, n0 = bx << 7;
  const int t = threadIdx.x, w = t >> 6, l = t & 63;
  const int wr = (w & 1) << 5, wc = (w >> 1) << 6;
  const int lr = l & 15, lg = l >> 4;
  const int g_row = l >> 2;
  const int g_col = (((l & 3) ^ ((l >> 3) & 3)) << 3);

  auto stage = [&](int buf, int kt) {
    const int k0_ = kt << 5;
    {
      int rowA = (w << 4) + g_row;
      gload16(&A[(m0 + rowA) * K + k0_ + g_col], (char*)As[buf] + w * 1024);
    }
#pragma unroll
    for (int it = 0; it < 2; ++it) {
      int seg = (w << 1) + it;
      int row = (seg << 4) + g_row;
      gload16(&BT[(n0 + row) * K + k0_ + g_col], (char*)Bs[buf] + seg * 1024);
    }
  };

  f32x4 acc[2][4] = {};

  stage(0, 0);
  stage(1, 1);

#pragma unroll
  for (int kt = 0; kt < 32; ++kt) {
    if (kt < 31) asm volatile("s_waitcnt vmcnt(3)" ::: "memory");
    else         asm volatile("s_waitcnt vmcnt(0)" ::: "memory");
    __builtin_amdgcn_s_barrier();
    __builtin_amdgcn_sched_barrier(0);
    if (kt < 30) stage((kt + 2) % 3, kt + 2);
    const u16* Ab = As[kt % 3];
    const u16* Bb = Bs[kt % 3];
    bf16x8 af[2], bfr[4];
#pragma unroll
    for (int m = 0; m < 2; ++m) af[m] = lds32(Ab, wr + (m << 4) + lr, lg);
#pragma unroll
    for (int n = 0; n < 4; ++n) bfr[n] = lds32(Bb, wc + (n << 4) + lr, lg);
#pragma unroll
    for (int m = 0; m < 2; ++m)
#pragma unroll
      for (int n = 0; n < 4; ++n)
        acc[m][n] = __builtin_amdgcn_mfma_f32_16x16x32_bf16(af[m], bfr[n], acc[m][n], 0, 0, 0);
  }

#pragma unroll
  for (int m = 0; m < 2; ++m)
#pragma unroll
    for (int n = 0; n < 4; ++n) {
      const int col = n0 + wc + (n << 4) + lr;
#pragma unroll
      for (int r = 0; r < 4; ++r) {
        const int row = m0 + wr + (m << 4) + (lg << 2) + r;
        C[row * 1024 + col] = acc[m][n][r];
      }
    }
}

// ---------------- flash attention (r15 — known best) ----------------
// grid 512 (XCD-swizzled), 256 threads = 4 waves; wave owns 32 q-rows (2 groups).
// Q in registers. K and sigma-V both in LDS. Super-tiles of 128 keys (2x64 sub-tiles):
// one stage + one vmcnt(0)+barrier per super-tile (16 phases). Zero-C softmax,
// in-register P via sigma permutation. Softmax denominator on the MATRIX pipe:
// Osum[g] = mfma(pa, ones, Osum[g]) — row-sums land pre-positioned at (lg*4+r).

__global__ __launch_bounds__(256) void attn_k(const u16* __restrict__ Qb,
                                              const u16* __restrict__ Kb,
                                              const u16* __restrict__ VbT,
                                              u16* __restrict__ Ob) {
  __shared__ u16 Ks[2][2][64 * 64];   // [buf][sub][key][dim]
  __shared__ u16 Vs[2][2][64 * 64];   // [buf][sub][dim][key-sigma]

  const int lin = blockIdx.x;
  const int xcd = lin & 7, rest = lin >> 3;
  const int bh = (xcd << 2) + (rest & 3);     // 4 bh per XCD -> K/V L2-resident
  const int qt = rest >> 2;                   // 0..15
  const int b = bh >> 4;
  const int t = threadIdx.x, w = t >> 6, l = t & 63;
  const int lr = l & 15, lg = l >> 4;
  const int rb = b << 11;
  const int cb = (bh & 15) << 6;
  const int srow = l >> 3;
  const int scol = ((l & 7) ^ srow) << 3;

  auto kv_stage = [&](int buf, int st) {
#pragma unroll
    for (int sub = 0; sub < 2; ++sub) {
      const int tile = (st << 1) + sub;
#pragma unroll
      for (int it = 0; it < 2; ++it) {
        int seg = (w << 1) + it;
        int row = (seg << 3) + srow;
        gload16(&Kb[(size_t)(rb + (tile << 6) + row) * 1024 + cb + scol],
                (char*)Ks[buf][sub] + seg * 1024);
        gload16(&VbT[(size_t)((bh << 6) + row) * 2048 + (tile << 6) + scol],
                (char*)Vs[buf][sub] + seg * 1024);
      }
    }
  };

  // Q direct to registers
  bf16x8 qf[2][2];
#pragma unroll
  for (int g = 0; g < 2; ++g)
#pragma unroll
    for (int kk = 0; kk < 2; ++kk)
      qf[g][kk] = *(const bf16x8*)&Qb[(size_t)(rb + (qt << 7) + (w << 5) + (g << 4) + lr) * 1024
                                      + cb + (kk << 5) + (lg << 3)];

  // bf16 1.0 x8 constant for the denominator MFMA
  bf16x8 vones;
  {
    u32x4 to; to[0] = 0x3F803F80u; to[1] = 0x3F803F80u; to[2] = 0x3F803F80u; to[3] = 0x3F803F80u;
    vones = *(const bf16x8*)&to;
  }

  kv_stage(0, 0);
  asm volatile("s_waitcnt vmcnt(0)" ::: "memory");
  __builtin_amdgcn_s_barrier();
  __builtin_amdgcn_sched_barrier(0);

  const f32x4 z4 = {0.f, 0.f, 0.f, 0.f};
  f32x4 Osum[2] = {};      // P row-sums (denominator), matrix pipe
  f32x4 Oacc[2][4] = {};   // [g][df]

  for (int st = 0; st < 16; ++st) {
    const int buf = st & 1;
    if (st < 15) kv_stage(buf ^ 1, st + 1);   // issued first: whole phase to land

#pragma unroll
    for (int sub = 0; sub < 2; ++sub) {
      const u16* Kc = Ks[buf][sub];
      const u16* Vc = Vs[buf][sub];

      unsigned U[2][4][2];   // [g][c][half]
#pragma unroll
      for (int c = 0; c < 4; ++c) {
        bf16x8 kf0 = lds8(Kc, (c << 4) + lr, (lg << 4));
        bf16x8 kf1 = lds8(Kc, (c << 4) + lr, 64 + (lg << 4));
        f32x4 S[2];
        __builtin_amdgcn_s_setprio(1);
#pragma unroll
        for (int g = 0; g < 2; ++g) {
          S[g] = __builtin_amdgcn_mfma_f32_16x16x32_bf16(kf0, qf[g][0], z4, 0, 0, 0);
          S[g] = __builtin_amdgcn_mfma_f32_16x16x32_bf16(kf1, qf[g][1], S[g], 0, 0, 0);
        }
        __builtin_amdgcn_s_setprio(0);
#pragma unroll
        for (int g = 0; g < 2; ++g) {
          float q0 = exp2v(S[g][0]), q1 = exp2v(S[g][1]);
          float q2 = exp2v(S[g][2]), q3 = exp2v(S[g][3]);
          U[g][c][0] = pk2bf(q0, q1);
          U[g][c][1] = pk2bf(q2, q3);
        }
      }

#pragma unroll
      for (int kk2 = 0; kk2 < 2; ++kk2) {
        bf16x8 vf[4];
#pragma unroll
        for (int df = 0; df < 4; ++df)
          vf[df] = lds8(Vc, (df << 4) + lr, (kk2 << 6) + (lg << 4));
        __builtin_amdgcn_s_setprio(1);
#pragma unroll
        for (int g = 0; g < 2; ++g) {
          u32x4 pt;
          pt[0] = U[g][2 * kk2][0];     pt[1] = U[g][2 * kk2][1];
          pt[2] = U[g][2 * kk2 + 1][0]; pt[3] = U[g][2 * kk2 + 1][1];
          bf16x8 pa = *(const bf16x8*)&pt;
#pragma unroll
          for (int df = 0; df < 4; ++df)
            Oacc[g][df] = __builtin_amdgcn_mfma_f32_16x16x32_bf16(pa, vf[df], Oacc[g][df], 0, 0, 0);
          Osum[g] = __builtin_amdgcn_mfma_f32_16x16x32_bf16(pa, vones, Osum[g], 0, 0, 0);
        }
        __builtin_amdgcn_s_setprio(0);
      }
    }

    asm volatile("s_waitcnt vmcnt(0)" ::: "memory");
    __builtin_amdgcn_s_barrier();
    __builtin_amdgcn_sched_barrier(0);
  }

  // epilogue: denominator already positioned at (lg*4+r) — no shuffles
#pragma unroll
  for (int g = 0; g < 2; ++g) {
    float lq[4];
#pragma unroll
    for (int r = 0; r < 4; ++r) lq[r] = 1.f / Osum[g][r];
#pragma unroll
    for (int df = 0; df < 4; ++df)
#pragma unroll
      for (int r = 0; r < 4; ++r) {
        int row = (qt << 7) + (w << 5) + (g << 4) + (lg << 2) + r;
        int col = (df << 4) + lr;
        Ob[(size_t)(rb + row) * 1024 + cb + col] = f2bf(Oacc[g][df][r] * lq[r]);
      }
  }
}

// ---------------- launcher ----------------

extern "C" void kernel_launch(void* const* d_in, const int* in_sizes, int n_in,
                              void* d_out, int out_size, void* d_ws, size_t ws_size,
                              hipStream_t stream) {
  const float* x  = (const float*)d_in[0];
  const float* Wq = (const float*)d_in[1];
  const float* Wk = (const float*)d_in[2];
  const float* Wv = (const float*)d_in[3];
  const float* Wo = (const float*)d_in[4];
  float* out = (float*)d_out;

  char* ws = (char*)d_ws;
  u16* xb     = (u16*)(ws);                 // 8 MB (reused as Ob)
  u16* WqkvT  = (u16*)(ws + 8388608);       // 6 MB  [3072][1024]
  u16* WoT    = (u16*)(ws + 14680064);      // 2 MB
  u16* Qb     = (u16*)(ws + 16777216);      // 8 MB
  u16* Kb     = (u16*)(ws + 25165824);      // 8 MB  row-major K
  u16* VbT    = (u16*)(ws + 33554432);      // 8 MB  [bh*64+dim][2048 pos, sigma]
  f32x2* ctab = (f32x2*)(ws + 41943040);    // 512 KB
  u16* Ob = xb;

  prep_k<<<3328, 256, 0, stream>>>(x, Wq, Wk, Wv, Wo, xb, WqkvT, WoT, ctab);

  gemm_qkv_k<<<768, 256, 0, stream>>>(xb, WqkvT, Qb, Kb, VbT, ctab);

  attn_k<<<512, 256, 0, stream>>>(Qb, Kb, VbT, Ob);

  gemm_out_k<<<512, 256, 0, stream>>>(Ob, WoT, out);
}

// Round 20
// 109.480 us; speedup vs baseline: 1.0959x; 1.0959x over previous
//
#include <hip/hip_runtime.h>

typedef unsigned short u16;
typedef short  bf16x8 __attribute__((ext_vector_type(8)));
typedef u16    u16x8  __attribute__((ext_vector_type(8)));
typedef float  f32x4  __attribute__((ext_vector_type(4)));
typedef float  f32x2  __attribute__((ext_vector_type(2)));
typedef int    i32x4  __attribute__((ext_vector_type(4)));
typedef unsigned u32x2 __attribute__((ext_vector_type(2)));
typedef unsigned u32x4 __attribute__((ext_vector_type(4)));

__device__ __forceinline__ u16 f2bf(float f) {
  union { float f; unsigned u; } x; x.f = f;
  return (u16)((x.u + 0x7fffu + ((x.u >> 16) & 1u)) >> 16);
}

__device__ __forceinline__ unsigned pk2bf(float a, float b) {
  unsigned r;
  asm("v_cvt_pk_bf16_f32 %0, %1, %2" : "=v"(r) : "v"(a), "v"(b));
  return r;
}

__device__ __forceinline__ float exp2v(float x) {
  float r;
  asm("v_exp_f32 %0, %1" : "=v"(r) : "v"(x));
  return r;
}

// async global->LDS, 16B per lane; lds base wave-uniform (HW adds lane*16)
__device__ __forceinline__ void gload16(const void* g, void* lds) {
  __builtin_amdgcn_global_load_lds((const __attribute__((address_space(1))) unsigned int*)g,
                                   (__attribute__((address_space(3))) unsigned int*)lds,
                                   16, 0, 0);
}

// ---- 64-col tiles (128B rows): XOR-swizzled b128 read (2-way max) ----
__device__ __forceinline__ bf16x8 lds8(const u16* base, int row, int colb) {
  int off = (row << 7) + colb;
  off ^= (row & 7) << 4;
  return *(const bf16x8*)((const char*)base + off);
}

// ---- 32-col tiles (64B rows): slot = lg ^ ((row>>1)&3), conflict-free (r16-proven).
// Write side uses g_row = l>>2, g_col = ((l&3) ^ ((l>>3)&3))*8 per 1KB (16-row) seg.
__device__ __forceinline__ bf16x8 lds32(const u16* base, int row, int lg) {
  int off = (row << 6) + ((lg ^ ((row >> 1) & 3)) << 4);
  return *(const bf16x8*)((const char*)base + off);
}

// ---------------- merged prep kernel ----------------

__global__ __launch_bounds__(256) void prep_k(const float* __restrict__ x,
                                              const float* __restrict__ Wq,
                                              const float* __restrict__ Wk,
                                              const float* __restrict__ Wv,
                                              const float* __restrict__ Wo,
                                              u16* __restrict__ xb,
                                              u16* __restrict__ WqkvT,
                                              u16* __restrict__ WoT,
                                              f32x2* __restrict__ ctab) {
  __shared__ u16 tile[64][72];
  const int bid = blockIdx.x;
  const int t = threadIdx.x;

  if (bid < 2048) {
    int i = (bid * 256 + t) * 8;
    float4 a = *(const float4*)&x[i];
    float4 b = *(const float4*)&x[i + 4];
    u16x8 o;
    o[0] = f2bf(a.x); o[1] = f2bf(a.y); o[2] = f2bf(a.z); o[3] = f2bf(a.w);
    o[4] = f2bf(b.x); o[5] = f2bf(b.y); o[6] = f2bf(b.z); o[7] = f2bf(b.w);
    *(u16x8*)&xb[i] = o;
  } else if (bid < 3072) {
    int b2 = bid - 2048;
    int z = b2 >> 8, rem = b2 & 255;
    int k0 = (rem >> 4) << 6, nn0 = (rem & 15) << 6;
    const float* W = (z == 0) ? Wq : (z == 1) ? Wk : (z == 2) ? Wv : Wo;
    u16* dst = (z < 3) ? (WqkvT + z * 1024 * 1024) : WoT;
#pragma unroll
    for (int p = 0; p < 4; ++p) {
      int kr = (p << 4) + (t >> 4), c4 = (t & 15) << 2;
      float4 v = *(const float4*)&W[(k0 + kr) * 1024 + nn0 + c4];
      tile[c4 + 0][kr] = f2bf(v.x); tile[c4 + 1][kr] = f2bf(v.y);
      tile[c4 + 2][kr] = f2bf(v.z); tile[c4 + 3][kr] = f2bf(v.w);
    }
    __syncthreads();
#pragma unroll
    for (int p = 0; p < 2; ++p) {
      int nr = (p << 5) + (t >> 3), c8 = (t & 7) << 3;
      i32x4 vv = *(const i32x4*)&tile[nr][c8];
      *(i32x4*)&dst[(nn0 + nr) * 1024 + k0 + c8] = vv;
    }
  } else {
    int idx = (bid - 3072) * 256 + t;
    int i = idx & 31, p = idx >> 5;
    float freq = powf(10000.0f, -(float)(2 * i) * (1.0f / 64.0f));
    float ang = (float)p * freq;
    f32x2 v; v[0] = cosf(ang); v[1] = sinf(ang);
    ctab[idx] = v;
  }
}

// ---------------- fused QKV GEMM (r16 structure + LDS-transpose V epilogue) ----------------
// 128x128 tile, BK=32, 3 LDS buffers, 2-deep prefetch, counted vmcnt, grid 768
// (1D, XCD swizzle: 4 M-rows x 24 N per XCD). Conflict-free LDS swizzle.
// n-region 0: Q (RoPE * 0.125*log2e), 1: K (RoPE), 2: V — transposed per-(b,h) with
// sigma key-permute via LDS transpose (coalesced 16B stores; layout identical to r16).
// V epilogue begins with __syncthreads(): sh is reused as Lt, and the main loop's
// last iteration has no trailing barrier (r19 race fix).

__global__ __launch_bounds__(256) void gemm_qkv_k(const u16* __restrict__ A,
                                                  const u16* __restrict__ BT,
                                                  u16* __restrict__ Qb,
                                                  u16* __restrict__ Kb,
                                                  u16* __restrict__ VbT,
                                                  const f32x2* __restrict__ ctab) {
  __shared__ u16 sh[24576];                 // 48KB: As[3][4096] | Bs[3][4096]; Lt overlay
  u16* const AsB = sh;                      // + buf*4096
  u16* const BsB = sh + 12288;
  const int K = 1024;
  const int lin = blockIdx.x;
  const int xcd = lin & 7, idx = lin >> 3;       // idx 0..95
  const int by = (xcd << 2) + idx / 24;          // 4 M-rows per XCD
  const int bx = idx % 24;
  const int m0 = by << 7, n0 = bx << 7;
  const int t = threadIdx.x, w = t >> 6, l = t & 63;
  const int wr = (w >> 1) << 6, wc = (w & 1) << 6;
  const int lr = l & 15, lg = l >> 4;
  const int g_row = l >> 2;
  const int g_col = (((l & 3) ^ ((l >> 3) & 3)) << 3);   // matches lds32 swizzle

  auto stage = [&](int buf, int kt) {
    const int k0_ = kt << 5;
#pragma unroll
    for (int it = 0; it < 2; ++it) {
      int seg = (w << 1) + it;
      int row = (seg << 4) + g_row;
      gload16(&A[(m0 + row) * K + k0_ + g_col], (char*)(AsB + buf * 4096) + seg * 1024);
      gload16(&BT[(n0 + row) * K + k0_ + g_col], (char*)(BsB + buf * 4096) + seg * 1024);
    }
  };

  f32x4 acc[4][4] = {};

  stage(0, 0);
  stage(1, 1);

#pragma unroll
  for (int kt = 0; kt < 32; ++kt) {
    if (kt < 31) asm volatile("s_waitcnt vmcnt(4)" ::: "memory");
    else         asm volatile("s_waitcnt vmcnt(0)" ::: "memory");
    __builtin_amdgcn_s_barrier();
    __builtin_amdgcn_sched_barrier(0);
    if (kt < 30) stage((kt + 2) % 3, kt + 2);
    const u16* Ab = AsB + (kt % 3) * 4096;
    const u16* Bb = BsB + (kt % 3) * 4096;
    bf16x8 af[4], bfr[4];
#pragma unroll
    for (int m = 0; m < 4; ++m) af[m] = lds32(Ab, wr + (m << 4) + lr, lg);
#pragma unroll
    for (int n = 0; n < 4; ++n) bfr[n] = lds32(Bb, wc + (n << 4) + lr, lg);
#pragma unroll
    for (int m = 0; m < 4; ++m)
#pragma unroll
      for (int n = 0; n < 4; ++n)
        acc[m][n] = __builtin_amdgcn_mfma_f32_16x16x32_bf16(af[m], bfr[n], acc[m][n], 0, 0, 0);
  }

  const int region = n0 >> 10;
  if (region < 2) {
    const float qscale = 0.125f * 1.44269504088896f;
#pragma unroll
    for (int m = 0; m < 4; ++m)
#pragma unroll
      for (int n = 0; n < 4; ++n) {
        const int col = n0 + wc + (n << 4) + lr;
        const int hd = col & 63;
#pragma unroll
        for (int r = 0; r < 4; ++r) {
          const int row = m0 + wr + (m << 4) + (lg << 2) + r;
          float v = acc[m][n][r];
          float p = __shfl_xor(v, 1);
          f32x2 cs = ctab[(row & 2047) * 32 + (hd >> 1)];
          float o = (hd & 1) ? (p * cs[1] + v * cs[0]) : (v * cs[0] - p * cs[1]);
          if (region == 0) { o *= qscale; Qb[row * 1024 + (col & 1023)] = f2bf(o); }
          else             { Kb[row * 1024 + (col & 1023)] = f2bf(o); }
        }
      }
  } else {
    // V: LDS transpose epilogue. Lt[dimLocal][posLocal], stride 132 u16 (33KB, fits).
    __syncthreads();   // RACE FIX: all waves done reading sh (kt=31 has no trailing barrier)
    u16* Lt = sh;
#pragma unroll
    for (int m = 0; m < 4; ++m)
#pragma unroll
      for (int n = 0; n < 4; ++n) {
        const int dL = wc + (n << 4) + lr;          // local dim 0..127
#pragma unroll
        for (int r = 0; r < 4; ++r) {
          const int pL = wr + (m << 4) + (lg << 2) + r;   // local pos 0..127
          Lt[dL * 132 + pL] = f2bf(acc[m][n][r]);
        }
      }
    __syncthreads();

    const int bb = m0 >> 11;                  // batch
    const int pbase0 = m0 & 2047;             // pos base within batch
    const int cvb = n0 - 2048;                // dim-region base (mult of 128)
#pragma unroll
    for (int i = 0; i < 8; ++i) {
      const int f = (i << 8) + t;             // 0..2047
      const int dL = f >> 4;                  // local dim 0..127
      const int h = (f >> 3) & 1;             // pos bit6
      const int q = f & 7;                    // posp sub-block
      const int bsrc = ((q & 3) << 2) + (((q >> 2) & 1) << 5) + (h << 6);
      u32x2 a = *(const u32x2*)&Lt[dL * 132 + bsrc];        // pos b..b+3
      u32x2 c = *(const u32x2*)&Lt[dL * 132 + bsrc + 16];   // pos b+16..b+19
      u32x4 sv; sv[0] = a[0]; sv[1] = a[1]; sv[2] = c[0]; sv[3] = c[1];
      const int cv = cvb + dL;
      const int R = (((bb << 4) + (cv >> 6)) << 6) | (cv & 63);
      *(u32x4*)&VbT[(size_t)R * 2048 + pbase0 + (h << 6) + (q << 3)] = sv;
    }
  }
}

// ---------------- output GEMM: out = Ob * WoT^T, fp32 out (r16) ----------------

__global__ __launch_bounds__(256) void gemm_out_k(const u16* __restrict__ A,
                                                  const u16* __restrict__ BT,
                                                  float* __restrict__ C) {
  __shared__ u16 As[3][64 * 32];
  __shared__ u16 Bs[3][128 * 32];
  const int K = 1024;
  const int lin = blockIdx.x;
  const int xcd = lin & 7, idx = lin >> 3;
  const int by = (xcd << 3) + (idx >> 3);
  const int bx = idx & 7;
  const int m0 = by << 6, n0 = bx << 7;
  const int t = threadIdx.x, w = t >> 6, l = t & 63;
  const int wr = (w & 1) << 5, wc = (w >> 1) << 6;
  const int lr = l & 15, lg = l >> 4;
  const int g_row = l >> 2;
  const int g_col = (((l & 3) ^ ((l >> 3) & 3)) << 3);

  auto stage = [&](int buf, int kt) {
    const int k0_ = kt << 5;
    {
      int rowA = (w << 4) + g_row;
      gload16(&A[(m0 + rowA) * K + k0_ + g_col], (char*)As[buf] + w * 1024);
    }
#pragma unroll
    for (int it = 0; it < 2; ++it) {
      int seg = (w << 1) + it;
      int row = (seg << 4) + g_row;
      gload16(&BT[(n0 + row) * K + k0_ + g_col], (char*)Bs[buf] + seg * 1024);
    }
  };

  f32x4 acc[2][4] = {};

  stage(0, 0);
  stage(1, 1);

#pragma unroll
  for (int kt = 0; kt < 32; ++kt) {
    if (kt < 31) asm volatile("s_waitcnt vmcnt(3)" ::: "memory");
    else         asm volatile("s_waitcnt vmcnt(0)" ::: "memory");
    __builtin_amdgcn_s_barrier();
    __builtin_amdgcn_sched_barrier(0);
    if (kt < 30) stage((kt + 2) % 3, kt + 2);
    const u16* Ab = As[kt % 3];
    const u16* Bb = Bs[kt % 3];
    bf16x8 af[2], bfr[4];
#pragma unroll
    for (int m = 0; m < 2; ++m) af[m] = lds32(Ab, wr + (m << 4) + lr, lg);
#pragma unroll
    for (int n = 0; n < 4; ++n) bfr[n] = lds32(Bb, wc + (n << 4) + lr, lg);
#pragma unroll
    for (int m = 0; m < 2; ++m)
#pragma unroll
      for (int n = 0; n < 4; ++n)
        acc[m][n] = __builtin_amdgcn_mfma_f32_16x16x32_bf16(af[m], bfr[n], acc[m][n], 0, 0, 0);
  }

#pragma unroll
  for (int m = 0; m < 2; ++m)
#pragma unroll
    for (int n = 0; n < 4; ++n) {
      const int col = n0 + wc + (n << 4) + lr;
#pragma unroll
      for (int r = 0; r < 4; ++r) {
        const int row = m0 + wr + (m << 4) + (lg << 2) + r;
        C[row * 1024 + col] = acc[m][n][r];
      }
    }
}

// ---------------- flash attention (r15/r16 — known best) ----------------
// grid 512 (XCD-swizzled), 256 threads = 4 waves; wave owns 32 q-rows (2 groups).
// Q in registers. K and sigma-V both in LDS. Super-tiles of 128 keys (2x64 sub-tiles):
// one stage + one vmcnt(0)+barrier per super-tile (16 phases). Zero-C softmax,
// in-register P via sigma permutation. Denominator on the MATRIX pipe (mfma ones).

__global__ __launch_bounds__(256) void attn_k(const u16* __restrict__ Qb,
                                              const u16* __restrict__ Kb,
                                              const u16* __restrict__ VbT,
                                              u16* __restrict__ Ob) {
  __shared__ u16 Ks[2][2][64 * 64];   // [buf][sub][key][dim]
  __shared__ u16 Vs[2][2][64 * 64];   // [buf][sub][dim][key-sigma]

  const int lin = blockIdx.x;
  const int xcd = lin & 7, rest = lin >> 3;
  const int bh = (xcd << 2) + (rest & 3);
  const int qt = rest >> 2;
  const int b = bh >> 4;
  const int t = threadIdx.x, w = t >> 6, l = t & 63;
  const int lr = l & 15, lg = l >> 4;
  const int rb = b << 11;
  const int cb = (bh & 15) << 6;
  const int srow = l >> 3;
  const int scol = ((l & 7) ^ srow) << 3;

  auto kv_stage = [&](int buf, int st) {
#pragma unroll
    for (int sub = 0; sub < 2; ++sub) {
      const int tile = (st << 1) + sub;
#pragma unroll
      for (int it = 0; it < 2; ++it) {
        int seg = (w << 1) + it;
        int row = (seg << 3) + srow;
        gload16(&Kb[(size_t)(rb + (tile << 6) + row) * 1024 + cb + scol],
                (char*)Ks[buf][sub] + seg * 1024);
        gload16(&VbT[(size_t)((bh << 6) + row) * 2048 + (tile << 6) + scol],
                (char*)Vs[buf][sub] + seg * 1024);
      }
    }
  };

  bf16x8 qf[2][2];
#pragma unroll
  for (int g = 0; g < 2; ++g)
#pragma unroll
    for (int kk = 0; kk < 2; ++kk)
      qf[g][kk] = *(const bf16x8*)&Qb[(size_t)(rb + (qt << 7) + (w << 5) + (g << 4) + lr) * 1024
                                      + cb + (kk << 5) + (lg << 3)];

  bf16x8 vones;
  {
    u32x4 to; to[0] = 0x3F803F80u; to[1] = 0x3F803F80u; to[2] = 0x3F803F80u; to[3] = 0x3F803F80u;
    vones = *(const bf16x8*)&to;
  }

  kv_stage(0, 0);
  asm volatile("s_waitcnt vmcnt(0)" ::: "memory");
  __builtin_amdgcn_s_barrier();
  __builtin_amdgcn_sched_barrier(0);

  const f32x4 z4 = {0.f, 0.f, 0.f, 0.f};
  f32x4 Osum[2] = {};
  f32x4 Oacc[2][4] = {};

  for (int st = 0; st < 16; ++st) {
    const int buf = st & 1;
    if (st < 15) kv_stage(buf ^ 1, st + 1);

#pragma unroll
    for (int sub = 0; sub < 2; ++sub) {
      const u16* Kc = Ks[buf][sub];
      const u16* Vc = Vs[buf][sub];

      unsigned U[2][4][2];
#pragma unroll
      for (int c = 0; c < 4; ++c) {
        bf16x8 kf0 = lds8(Kc, (c << 4) + lr, (lg << 4));
        bf16x8 kf1 = lds8(Kc, (c << 4) + lr, 64 + (lg << 4));
        f32x4 S[2];
        __builtin_amdgcn_s_setprio(1);
#pragma unroll
        for (int g = 0; g < 2; ++g) {
          S[g] = __builtin_amdgcn_mfma_f32_16x16x32_bf16(kf0, qf[g][0], z4, 0, 0, 0);
          S[g] = __builtin_amdgcn_mfma_f32_16x16x32_bf16(kf1, qf[g][1], S[g], 0, 0, 0);
        }
        __builtin_amdgcn_s_setprio(0);
#pragma unroll
        for (int g = 0; g < 2; ++g) {
          float q0 = exp2v(S[g][0]), q1 = exp2v(S[g][1]);
          float q2 = exp2v(S[g][2]), q3 = exp2v(S[g][3]);
          U[g][c][0] = pk2bf(q0, q1);
          U[g][c][1] = pk2bf(q2, q3);
        }
      }

#pragma unroll
      for (int kk2 = 0; kk2 < 2; ++kk2) {
        bf16x8 vf[4];
#pragma unroll
        for (int df = 0; df < 4; ++df)
          vf[df] = lds8(Vc, (df << 4) + lr, (kk2 << 6) + (lg << 4));
        __builtin_amdgcn_s_setprio(1);
#pragma unroll
        for (int g = 0; g < 2; ++g) {
          u32x4 pt;
          pt[0] = U[g][2 * kk2][0];     pt[1] = U[g][2 * kk2][1];
          pt[2] = U[g][2 * kk2 + 1][0]; pt[3] = U[g][2 * kk2 + 1][1];
          bf16x8 pa = *(const bf16x8*)&pt;
#pragma unroll
          for (int df = 0; df < 4; ++df)
            Oacc[g][df] = __builtin_amdgcn_mfma_f32_16x16x32_bf16(pa, vf[df], Oacc[g][df], 0, 0, 0);
          Osum[g] = __builtin_amdgcn_mfma_f32_16x16x32_bf16(pa, vones, Osum[g], 0, 0, 0);
        }
        __builtin_amdgcn_s_setprio(0);
      }
    }

    asm volatile("s_waitcnt vmcnt(0)" ::: "memory");
    __builtin_amdgcn_s_barrier();
    __builtin_amdgcn_sched_barrier(0);
  }

#pragma unroll
  for (int g = 0; g < 2; ++g) {
    float lq[4];
#pragma unroll
    for (int r = 0; r < 4; ++r) lq[r] = 1.f / Osum[g][r];
#pragma unroll
    for (int df = 0; df < 4; ++df)
#pragma unroll
      for (int r = 0; r < 4; ++r) {
        int row = (qt << 7) + (w << 5) + (g << 4) + (lg << 2) + r;
        int col = (df << 4) + lr;
        Ob[(size_t)(rb + row) * 1024 + cb + col] = f2bf(Oacc[g][df][r] * lq[r]);
      }
  }
}

// ---------------- launcher ----------------

extern "C" void kernel_launch(void* const* d_in, const int* in_sizes, int n_in,
                              void* d_out, int out_size, void* d_ws, size_t ws_size,
                              hipStream_t stream) {
  const float* x  = (const float*)d_in[0];
  const float* Wq = (const float*)d_in[1];
  const float* Wk = (const float*)d_in[2];
  const float* Wv = (const float*)d_in[3];
  const float* Wo = (const float*)d_in[4];
  float* out = (float*)d_out;

  char* ws = (char*)d_ws;
  u16* xb     = (u16*)(ws);                 // 8 MB (reused as Ob)
  u16* WqkvT  = (u16*)(ws + 8388608);       // 6 MB  [3072][1024]
  u16* WoT    = (u16*)(ws + 14680064);      // 2 MB
  u16* Qb     = (u16*)(ws + 16777216);      // 8 MB
  u16* Kb     = (u16*)(ws + 25165824);      // 8 MB  row-major K
  u16* VbT    = (u16*)(ws + 33554432);      // 8 MB  [bh*64+dim][2048 pos, sigma]
  f32x2* ctab = (f32x2*)(ws + 41943040);    // 512 KB
  u16* Ob = xb;

  prep_k<<<3328, 256, 0, stream>>>(x, Wq, Wk, Wv, Wo, xb, WqkvT, WoT, ctab);

  gemm_qkv_k<<<768, 256, 0, stream>>>(xb, WqkvT, Qb, Kb, VbT, ctab);

  attn_k<<<512, 256, 0, stream>>>(Qb, Kb, VbT, Ob);

  gemm_out_k<<<512, 256, 0, stream>>>(Ob, WoT, out);
}

// Round 23
// 108.820 us; speedup vs baseline: 1.1025x; 1.0061x over previous
//
#include <hip/hip_runtime.h>

typedef unsigned short u16;
typedef short  bf16x8 __attribute__((ext_vector_type(8)));
typedef u16    u16x8  __attribute__((ext_vector_type(8)));
typedef float  f32x4  __attribute__((ext_vector_type(4)));
typedef float  f32x2  __attribute__((ext_vector_type(2)));
typedef int    i32x4  __attribute__((ext_vector_type(4)));
typedef unsigned u32x2 __attribute__((ext_vector_type(2)));
typedef unsigned u32x4 __attribute__((ext_vector_type(4)));

__device__ __forceinline__ u16 f2bf(float f) {
  union { float f; unsigned u; } x; x.f = f;
  return (u16)((x.u + 0x7fffu + ((x.u >> 16) & 1u)) >> 16);
}

__device__ __forceinline__ unsigned pk2bf(float a, float b) {
  unsigned r;
  asm("v_cvt_pk_bf16_f32 %0, %1, %2" : "=v"(r) : "v"(a), "v"(b));
  return r;
}

__device__ __forceinline__ float exp2v(float x) {
  float r;
  asm("v_exp_f32 %0, %1" : "=v"(r) : "v"(x));
  return r;
}

// async global->LDS, 16B per lane; lds base wave-uniform (HW adds lane*16)
__device__ __forceinline__ void gload16(const void* g, void* lds) {
  __builtin_amdgcn_global_load_lds((const __attribute__((address_space(1))) unsigned int*)g,
                                   (__attribute__((address_space(3))) unsigned int*)lds,
                                   16, 0, 0);
}

// ---- 64-col tiles (128B rows): XOR-swizzled b128 read (2-way max) ----
__device__ __forceinline__ bf16x8 lds8(const u16* base, int row, int colb) {
  int off = (row << 7) + colb;
  off ^= (row & 7) << 4;
  return *(const bf16x8*)((const char*)base + off);
}

// ---- 32-col tiles (64B rows): slot = lg ^ ((row>>1)&3), conflict-free (r16-proven).
// Write side uses g_row = l>>2, g_col = ((l&3) ^ ((l>>3)&3))*8 per 1KB (16-row) seg.
__device__ __forceinline__ bf16x8 lds32(const u16* base, int row, int lg) {
  int off = (row << 6) + ((lg ^ ((row >> 1) & 3)) << 4);
  return *(const bf16x8*)((const char*)base + off);
}

// ---------------- merged prep kernel ----------------

__global__ __launch_bounds__(256) void prep_k(const float* __restrict__ x,
                                              const float* __restrict__ Wq,
                                              const float* __restrict__ Wk,
                                              const float* __restrict__ Wv,
                                              const float* __restrict__ Wo,
                                              u16* __restrict__ xb,
                                              u16* __restrict__ WqkvT,
                                              u16* __restrict__ WoT,
                                              f32x2* __restrict__ ctab) {
  __shared__ u16 tile[64][72];
  const int bid = blockIdx.x;
  const int t = threadIdx.x;

  if (bid < 2048) {
    int i = (bid * 256 + t) * 8;
    float4 a = *(const float4*)&x[i];
    float4 b = *(const float4*)&x[i + 4];
    u16x8 o;
    o[0] = f2bf(a.x); o[1] = f2bf(a.y); o[2] = f2bf(a.z); o[3] = f2bf(a.w);
    o[4] = f2bf(b.x); o[5] = f2bf(b.y); o[6] = f2bf(b.z); o[7] = f2bf(b.w);
    *(u16x8*)&xb[i] = o;
  } else if (bid < 3072) {
    int b2 = bid - 2048;
    int z = b2 >> 8, rem = b2 & 255;
    int k0 = (rem >> 4) << 6, nn0 = (rem & 15) << 6;
    const float* W = (z == 0) ? Wq : (z == 1) ? Wk : (z == 2) ? Wv : Wo;
    u16* dst = (z < 3) ? (WqkvT + z * 1024 * 1024) : WoT;
#pragma unroll
    for (int p = 0; p < 4; ++p) {
      int kr = (p << 4) + (t >> 4), c4 = (t & 15) << 2;
      float4 v = *(const float4*)&W[(k0 + kr) * 1024 + nn0 + c4];
      tile[c4 + 0][kr] = f2bf(v.x); tile[c4 + 1][kr] = f2bf(v.y);
      tile[c4 + 2][kr] = f2bf(v.z); tile[c4 + 3][kr] = f2bf(v.w);
    }
    __syncthreads();
#pragma unroll
    for (int p = 0; p < 2; ++p) {
      int nr = (p << 5) + (t >> 3), c8 = (t & 7) << 3;
      i32x4 vv = *(const i32x4*)&tile[nr][c8];
      *(i32x4*)&dst[(nn0 + nr) * 1024 + k0 + c8] = vv;
    }
  } else {
    int idx = (bid - 3072) * 256 + t;
    int i = idx & 31, p = idx >> 5;
    float freq = powf(10000.0f, -(float)(2 * i) * (1.0f / 64.0f));
    float ang = (float)p * freq;
    f32x2 v; v[0] = cosf(ang); v[1] = sinf(ang);
    ctab[idx] = v;
  }
}

// ---------------- fused QKV GEMM (r16 structure + LDS-transpose V epilogue) ----------------
// 128x128 tile, BK=32, 3 LDS buffers, 2-deep prefetch, counted vmcnt, grid 768
// (1D, XCD swizzle: 4 M-rows x 24 N per XCD). Conflict-free LDS swizzle.
// n-region 0: Q (RoPE * 0.125*log2e), 1: K (RoPE), 2: V — transposed per-(b,h) with
// sigma key-permute via LDS transpose (coalesced 16B stores).
// V epilogue begins with __syncthreads(): sh is reused as Lt, and the main loop's
// last iteration has no trailing barrier (r19 race fix).

__global__ __launch_bounds__(256) void gemm_qkv_k(const u16* __restrict__ A,
                                                  const u16* __restrict__ BT,
                                                  u16* __restrict__ Qb,
                                                  u16* __restrict__ Kb,
                                                  u16* __restrict__ VbT,
                                                  const f32x2* __restrict__ ctab) {
  __shared__ u16 sh[24576];                 // 48KB: As[3][4096] | Bs[3][4096]; Lt overlay
  u16* const AsB = sh;                      // + buf*4096
  u16* const BsB = sh + 12288;
  const int K = 1024;
  const int lin = blockIdx.x;
  const int xcd = lin & 7, idx = lin >> 3;       // idx 0..95
  const int by = (xcd << 2) + idx / 24;          // 4 M-rows per XCD
  const int bx = idx % 24;
  const int m0 = by << 7, n0 = bx << 7;
  const int t = threadIdx.x, w = t >> 6, l = t & 63;
  const int wr = (w >> 1) << 6, wc = (w & 1) << 6;
  const int lr = l & 15, lg = l >> 4;
  const int g_row = l >> 2;
  const int g_col = (((l & 3) ^ ((l >> 3) & 3)) << 3);   // matches lds32 swizzle

  auto stage = [&](int buf, int kt) {
    const int k0_ = kt << 5;
#pragma unroll
    for (int it = 0; it < 2; ++it) {
      int seg = (w << 1) + it;
      int row = (seg << 4) + g_row;
      gload16(&A[(m0 + row) * K + k0_ + g_col], (char*)(AsB + buf * 4096) + seg * 1024);
      gload16(&BT[(n0 + row) * K + k0_ + g_col], (char*)(BsB + buf * 4096) + seg * 1024);
    }
  };

  f32x4 acc[4][4] = {};

  stage(0, 0);
  stage(1, 1);

#pragma unroll
  for (int kt = 0; kt < 32; ++kt) {
    if (kt < 31) asm volatile("s_waitcnt vmcnt(4)" ::: "memory");
    else         asm volatile("s_waitcnt vmcnt(0)" ::: "memory");
    __builtin_amdgcn_s_barrier();
    __builtin_amdgcn_sched_barrier(0);
    if (kt < 30) stage((kt + 2) % 3, kt + 2);
    const u16* Ab = AsB + (kt % 3) * 4096;
    const u16* Bb = BsB + (kt % 3) * 4096;
    bf16x8 af[4], bfr[4];
#pragma unroll
    for (int m = 0; m < 4; ++m) af[m] = lds32(Ab, wr + (m << 4) + lr, lg);
#pragma unroll
    for (int n = 0; n < 4; ++n) bfr[n] = lds32(Bb, wc + (n << 4) + lr, lg);
#pragma unroll
    for (int m = 0; m < 4; ++m)
#pragma unroll
      for (int n = 0; n < 4; ++n)
        acc[m][n] = __builtin_amdgcn_mfma_f32_16x16x32_bf16(af[m], bfr[n], acc[m][n], 0, 0, 0);
  }

  const int region = n0 >> 10;
  if (region < 2) {
    const float qscale = 0.125f * 1.44269504088896f;
#pragma unroll
    for (int m = 0; m < 4; ++m)
#pragma unroll
      for (int n = 0; n < 4; ++n) {
        const int col = n0 + wc + (n << 4) + lr;
        const int hd = col & 63;
#pragma unroll
        for (int r = 0; r < 4; ++r) {
          const int row = m0 + wr + (m << 4) + (lg << 2) + r;
          float v = acc[m][n][r];
          float p = __shfl_xor(v, 1);
          f32x2 cs = ctab[(row & 2047) * 32 + (hd >> 1)];
          float o = (hd & 1) ? (p * cs[1] + v * cs[0]) : (v * cs[0] - p * cs[1]);
          if (region == 0) { o *= qscale; Qb[row * 1024 + (col & 1023)] = f2bf(o); }
          else             { Kb[row * 1024 + (col & 1023)] = f2bf(o); }
        }
      }
  } else {
    // V: LDS transpose epilogue. Lt[dimLocal][posLocal], stride 132 u16 (33KB, fits).
    __syncthreads();   // RACE FIX: all waves done reading sh (kt=31 has no trailing barrier)
    u16* Lt = sh;
#pragma unroll
    for (int m = 0; m < 4; ++m)
#pragma unroll
      for (int n = 0; n < 4; ++n) {
        const int dL = wc + (n << 4) + lr;          // local dim 0..127
#pragma unroll
        for (int r = 0; r < 4; ++r) {
          const int pL = wr + (m << 4) + (lg << 2) + r;   // local pos 0..127
          Lt[dL * 132 + pL] = f2bf(acc[m][n][r]);
        }
      }
    __syncthreads();

    const int bb = m0 >> 11;                  // batch
    const int pbase0 = m0 & 2047;             // pos base within batch
    const int cvb = n0 - 2048;                // dim-region base (mult of 128)
#pragma unroll
    for (int i = 0; i < 8; ++i) {
      const int f = (i << 8) + t;             // 0..2047
      const int dL = f >> 4;                  // local dim 0..127
      const int h = (f >> 3) & 1;             // pos bit6
      const int q = f & 7;                    // posp sub-block
      const int bsrc = ((q & 3) << 2) + (((q >> 2) & 1) << 5) + (h << 6);
      u32x2 a = *(const u32x2*)&Lt[dL * 132 + bsrc];        // pos b..b+3
      u32x2 c = *(const u32x2*)&Lt[dL * 132 + bsrc + 16];   // pos b+16..b+19
      u32x4 sv; sv[0] = a[0]; sv[1] = a[1]; sv[2] = c[0]; sv[3] = c[1];
      const int cv = cvb + dL;
      const int R = (((bb << 4) + (cv >> 6)) << 6) | (cv & 63);
      *(u32x4*)&VbT[(size_t)R * 2048 + pbase0 + (h << 6) + (q << 3)] = sv;
    }
  }
}

// ---------------- output GEMM: out = Ob * WoT^T, fp32 out (r16) ----------------

__global__ __launch_bounds__(256) void gemm_out_k(const u16* __restrict__ A,
                                                  const u16* __restrict__ BT,
                                                  float* __restrict__ C) {
  __shared__ u16 As[3][64 * 32];
  __shared__ u16 Bs[3][128 * 32];
  const int K = 1024;
  const int lin = blockIdx.x;
  const int xcd = lin & 7, idx = lin >> 3;
  const int by = (xcd << 3) + (idx >> 3);
  const int bx = idx & 7;
  const int m0 = by << 6, n0 = bx << 7;
  const int t = threadIdx.x, w = t >> 6, l = t & 63;
  const int wr = (w & 1) << 5, wc = (w >> 1) << 6;
  const int lr = l & 15, lg = l >> 4;
  const int g_row = l >> 2;
  const int g_col = (((l & 3) ^ ((l >> 3) & 3)) << 3);

  auto stage = [&](int buf, int kt) {
    const int k0_ = kt << 5;
    {
      int rowA = (w << 4) + g_row;
      gload16(&A[(m0 + rowA) * K + k0_ + g_col], (char*)As[buf] + w * 1024);
    }
#pragma unroll
    for (int it = 0; it < 2; ++it) {
      int seg = (w << 1) + it;
      int row = (seg << 4) + g_row;
      gload16(&BT[(n0 + row) * K + k0_ + g_col], (char*)Bs[buf] + seg * 1024);
    }
  };

  f32x4 acc[2][4] = {};

  stage(0, 0);
  stage(1, 1);

#pragma unroll
  for (int kt = 0; kt < 32; ++kt) {
    if (kt < 31) asm volatile("s_waitcnt vmcnt(3)" ::: "memory");
    else         asm volatile("s_waitcnt vmcnt(0)" ::: "memory");
    __builtin_amdgcn_s_barrier();
    __builtin_amdgcn_sched_barrier(0);
    if (kt < 30) stage((kt + 2) % 3, kt + 2);
    const u16* Ab = As[kt % 3];
    const u16* Bb = Bs[kt % 3];
    bf16x8 af[2], bfr[4];
#pragma unroll
    for (int m = 0; m < 2; ++m) af[m] = lds32(Ab, wr + (m << 4) + lr, lg);
#pragma unroll
    for (int n = 0; n < 4; ++n) bfr[n] = lds32(Bb, wc + (n << 4) + lr, lg);
#pragma unroll
    for (int m = 0; m < 2; ++m)
#pragma unroll
      for (int n = 0; n < 4; ++n)
        acc[m][n] = __builtin_amdgcn_mfma_f32_16x16x32_bf16(af[m], bfr[n], acc[m][n], 0, 0, 0);
  }

#pragma unroll
  for (int m = 0; m < 2; ++m)
#pragma unroll
    for (int n = 0; n < 4; ++n) {
      const int col = n0 + wc + (n << 4) + lr;
#pragma unroll
      for (int r = 0; r < 4; ++r) {
        const int row = m0 + wr + (m << 4) + (lg << 2) + r;
        C[row * 1024 + col] = acc[m][n][r];
      }
    }
}

// ---------------- flash attention (r15/r16 — known best) ----------------
// grid 512 (XCD-swizzled), 256 threads = 4 waves; wave owns 32 q-rows (2 groups).
// Q in registers. K and sigma-V both in LDS. Super-tiles of 128 keys (2x64 sub-tiles):
// one stage + one vmcnt(0)+barrier per super-tile (16 phases). Zero-C softmax,
// in-register P via sigma permutation. Denominator on the MATRIX pipe (mfma ones).

__global__ __launch_bounds__(256) void attn_k(const u16* __restrict__ Qb,
                                              const u16* __restrict__ Kb,
                                              const u16* __restrict__ VbT,
                                              u16* __restrict__ Ob) {
  __shared__ u16 Ks[2][2][64 * 64];   // [buf][sub][key][dim]
  __shared__ u16 Vs[2][2][64 * 64];   // [buf][sub][dim][key-sigma]

  const int lin = blockIdx.x;
  const int xcd = lin & 7, rest = lin >> 3;
  const int bh = (xcd << 2) + (rest & 3);
  const int qt = rest >> 2;
  const int b = bh >> 4;
  const int t = threadIdx.x, w = t >> 6, l = t & 63;
  const int lr = l & 15, lg = l >> 4;
  const int rb = b << 11;
  const int cb = (bh & 15) << 6;
  const int srow = l >> 3;
  const int scol = ((l & 7) ^ srow) << 3;

  auto kv_stage = [&](int buf, int st) {
#pragma unroll
    for (int sub = 0; sub < 2; ++sub) {
      const int tile = (st << 1) + sub;
#pragma unroll
      for (int it = 0; it < 2; ++it) {
        int seg = (w << 1) + it;
        int row = (seg << 3) + srow;
        gload16(&Kb[(size_t)(rb + (tile << 6) + row) * 1024 + cb + scol],
                (char*)Ks[buf][sub] + seg * 1024);
        gload16(&VbT[(size_t)((bh << 6) + row) * 2048 + (tile << 6) + scol],
                (char*)Vs[buf][sub] + seg * 1024);
      }
    }
  };

  bf16x8 qf[2][2];
#pragma unroll
  for (int g = 0; g < 2; ++g)
#pragma unroll
    for (int kk = 0; kk < 2; ++kk)
      qf[g][kk] = *(const bf16x8*)&Qb[(size_t)(rb + (qt << 7) + (w << 5) + (g << 4) + lr) * 1024
                                      + cb + (kk << 5) + (lg << 3)];

  bf16x8 vones;
  {
    u32x4 to; to[0] = 0x3F803F80u; to[1] = 0x3F803F80u; to[2] = 0x3F803F80u; to[3] = 0x3F803F80u;
    vones = *(const bf16x8*)&to;
  }

  kv_stage(0, 0);
  asm volatile("s_waitcnt vmcnt(0)" ::: "memory");
  __builtin_amdgcn_s_barrier();
  __builtin_amdgcn_sched_barrier(0);

  const f32x4 z4 = {0.f, 0.f, 0.f, 0.f};
  f32x4 Osum[2] = {};
  f32x4 Oacc[2][4] = {};

  for (int st = 0; st < 16; ++st) {
    const int buf = st & 1;
    if (st < 15) kv_stage(buf ^ 1, st + 1);

#pragma unroll
    for (int sub = 0; sub < 2; ++sub) {
      const u16* Kc = Ks[buf][sub];
      const u16* Vc = Vs[buf][sub];

      unsigned U[2][4][2];
#pragma unroll
      for (int c = 0; c < 4; ++c) {
        bf16x8 kf0 = lds8(Kc, (c << 4) + lr, (lg << 4));
        bf16x8 kf1 = lds8(Kc, (c << 4) + lr, 64 + (lg << 4));
        f32x4 S[2];
        __builtin_amdgcn_s_setprio(1);
#pragma unroll
        for (int g = 0; g < 2; ++g) {
          S[g] = __builtin_amdgcn_mfma_f32_16x16x32_bf16(kf0, qf[g][0], z4, 0, 0, 0);
          S[g] = __builtin_amdgcn_mfma_f32_16x16x32_bf16(kf1, qf[g][1], S[g], 0, 0, 0);
        }
        __builtin_amdgcn_s_setprio(0);
#pragma unroll
        for (int g = 0; g < 2; ++g) {
          float q0 = exp2v(S[g][0]), q1 = exp2v(S[g][1]);
          float q2 = exp2v(S[g][2]), q3 = exp2v(S[g][3]);
          U[g][c][0] = pk2bf(q0, q1);
          U[g][c][1] = pk2bf(q2, q3);
        }
      }

#pragma unroll
      for (int kk2 = 0; kk2 < 2; ++kk2) {
        bf16x8 vf[4];
#pragma unroll
        for (int df = 0; df < 4; ++df)
          vf[df] = lds8(Vc, (df << 4) + lr, (kk2 << 6) + (lg << 4));
        __builtin_amdgcn_s_setprio(1);
#pragma unroll
        for (int g = 0; g < 2; ++g) {
          u32x4 pt;
          pt[0] = U[g][2 * kk2][0];     pt[1] = U[g][2 * kk2][1];
          pt[2] = U[g][2 * kk2 + 1][0]; pt[3] = U[g][2 * kk2 + 1][1];
          bf16x8 pa = *(const bf16x8*)&pt;
#pragma unroll
          for (int df = 0; df < 4; ++df)
            Oacc[g][df] = __builtin_amdgcn_mfma_f32_16x16x32_bf16(pa, vf[df], Oacc[g][df], 0, 0, 0);
          Osum[g] = __builtin_amdgcn_mfma_f32_16x16x32_bf16(pa, vones, Osum[g], 0, 0, 0);
        }
        __builtin_amdgcn_s_setprio(0);
      }
    }

    asm volatile("s_waitcnt vmcnt(0)" ::: "memory");
    __builtin_amdgcn_s_barrier();
    __builtin_amdgcn_sched_barrier(0);
  }

#pragma unroll
  for (int g = 0; g < 2; ++g) {
    float lq[4];
#pragma unroll
    for (int r = 0; r < 4; ++r) lq[r] = 1.f / Osum[g][r];
#pragma unroll
    for (int df = 0; df < 4; ++df)
#pragma unroll
      for (int r = 0; r < 4; ++r) {
        int row = (qt << 7) + (w << 5) + (g << 4) + (lg << 2) + r;
        int col = (df << 4) + lr;
        Ob[(size_t)(rb + row) * 1024 + cb + col] = f2bf(Oacc[g][df][r] * lq[r]);
      }
  }
}

// ---------------- launcher ----------------

extern "C" void kernel_launch(void* const* d_in, const int* in_sizes, int n_in,
                              void* d_out, int out_size, void* d_ws, size_t ws_size,
                              hipStream_t stream) {
  const float* x  = (const float*)d_in[0];
  const float* Wq = (const float*)d_in[1];
  const float* Wk = (const float*)d_in[2];
  const float* Wv = (const float*)d_in[3];
  const float* Wo = (const float*)d_in[4];
  float* out = (float*)d_out;

  char* ws = (char*)d_ws;
  u16* xb     = (u16*)(ws);                 // 8 MB (reused as Ob)
  u16* WqkvT  = (u16*)(ws + 8388608);       // 6 MB  [3072][1024]
  u16* WoT    = (u16*)(ws + 14680064);      // 2 MB
  u16* Qb     = (u16*)(ws + 16777216);      // 8 MB
  u16* Kb     = (u16*)(ws + 25165824);      // 8 MB  row-major K
  u16* VbT    = (u16*)(ws + 33554432);      // 8 MB  [bh*64+dim][2048 pos, sigma]
  f32x2* ctab = (f32x2*)(ws + 41943040);    // 512 KB
  u16* Ob = xb;

  prep_k<<<3328, 256, 0, stream>>>(x, Wq, Wk, Wv, Wo, xb, WqkvT, WoT, ctab);

  gemm_qkv_k<<<768, 256, 0, stream>>>(xb, WqkvT, Qb, Kb, VbT, ctab);

  attn_k<<<512, 256, 0, stream>>>(Qb, Kb, VbT, Ob);

  gemm_out_k<<<512, 256, 0, stream>>>(Ob, WoT, out);
}